// Round 5
// baseline (387.581 us; speedup 1.0000x reference)
//
#include <hip/hip_runtime.h>

#define N_NODES 131072
#define C_IN 32
#define C_OUT 32
#define KTAPS 27
#define BN_EPS 1e-5f
#define NPASS 3

typedef __bf16 bf16x8 __attribute__((ext_vector_type(8)));
typedef float  f32x4  __attribute__((ext_vector_type(4)));

// ws layout:
//   xb   : (N_NODES+1) rows x 32 bf16  (row N_NODES = zeros, gather dummy target)
//   wlay : 27 taps x 2 co-halves x 64 lanes x 8 bf16  (55296 B)
//   sums : 32 sum + 32 sumsq (f32)

static __device__ __forceinline__ unsigned short f2bf(float f) {
    unsigned int u = __float_as_uint(f);
    unsigned int r = (u + 0x7FFFu + ((u >> 16) & 1u)) >> 16;  // RNE
    return (unsigned short)r;
}

// ---- prep: x transpose -> node-major bf16; block 0 also builds wlay + zero row ----
__global__ __launch_bounds__(256) void k_prep(const float* __restrict__ in,
                                              const float* __restrict__ w,
                                              unsigned short* __restrict__ xb,
                                              unsigned short* __restrict__ wlay) {
    const int n = blockIdx.x * 256 + threadIdx.x;
    unsigned short v[C_IN];
#pragma unroll
    for (int c = 0; c < C_IN; ++c) v[c] = f2bf(in[(size_t)c * N_NODES + n]);
    uint4* dst = reinterpret_cast<uint4*>(xb + (size_t)n * C_IN);
#pragma unroll
    for (int q = 0; q < 4; ++q) {
        uint4 pk;
        pk.x = (unsigned)v[q * 8 + 0] | ((unsigned)v[q * 8 + 1] << 16);
        pk.y = (unsigned)v[q * 8 + 2] | ((unsigned)v[q * 8 + 3] << 16);
        pk.z = (unsigned)v[q * 8 + 4] | ((unsigned)v[q * 8 + 5] << 16);
        pk.w = (unsigned)v[q * 8 + 6] | ((unsigned)v[q * 8 + 7] << 16);
        dst[q] = pk;
    }
    if (blockIdx.x == 0) {
        if (threadIdx.x < 4) {
            uint4 z = {0u, 0u, 0u, 0u};
            reinterpret_cast<uint4*>(xb + (size_t)N_NODES * C_IN)[threadIdx.x] = z;
        }
        for (int g = threadIdx.x; g < KTAPS * 2 * 64; g += 256) {
            const int k = g >> 7;
            const int rem = g & 127;
            const int h = rem >> 6;
            const int l = rem & 63;
            unsigned short wv[8];
#pragma unroll
            for (int j = 0; j < 8; ++j) {
                const int c  = ((l >> 4) << 3) + j;
                const int co = (h << 4) + (l & 15);
                wv[j] = f2bf(w[(size_t)(k * C_IN + c) * C_OUT + co]);
            }
            uint4 pk;
            pk.x = (unsigned)wv[0] | ((unsigned)wv[1] << 16);
            pk.y = (unsigned)wv[2] | ((unsigned)wv[3] << 16);
            pk.z = (unsigned)wv[4] | ((unsigned)wv[5] << 16);
            pk.w = (unsigned)wv[6] | ((unsigned)wv[7] << 16);
            *reinterpret_cast<uint4*>(wlay + (size_t)g * 8) = pk;
        }
    }
}

// ---- conv: 3-pass L2-resident gather, fully co-resident grid (8 blk/CU, VGPR<=64) ----
__global__ __launch_bounds__(256, 8) void k_conv_mfma(const unsigned short* __restrict__ xb,
                                                      const int* __restrict__ neigh,
                                                      const unsigned short* __restrict__ wlay,
                                                      float* __restrict__ out,
                                                      float* __restrict__ sums) {
    __shared__ int   nl[64 * KTAPS];   // block's neighbor lists (6912 B)
    __shared__ float bs[C_OUT];
    __shared__ float bq[C_OUT];

    // stage neigh for the block's 64 nodes (contiguous, coalesced)
    {
        const int* src = neigh + (size_t)blockIdx.x * 64 * KTAPS;
        for (int i = threadIdx.x; i < 64 * KTAPS; i += 256) nl[i] = src[i];
    }
    if (threadIdx.x < C_OUT) { bs[threadIdx.x] = 0.f; bq[threadIdx.x] = 0.f; }
    __syncthreads();

    const int wid  = threadIdx.x >> 6;
    const int lane = threadIdx.x & 63;
    const int lr   = lane & 15;   // node offset (B/D col)
    const int lg   = lane >> 4;   // channel-slice group
    const int node = wid * 16 + lr;               // node within block
    const int nb   = blockIdx.x * 64;             // block's first node

    f32x4 acc0 = {0.f, 0.f, 0.f, 0.f};
    f32x4 acc1 = {0.f, 0.f, 0.f, 0.f};

#pragma unroll 1
    for (int p = 0; p < NPASS; ++p) {
        const int lo = (p * N_NODES) / NPASS;
        const int hi = ((p + 1) * N_NODES) / NPASS;
#pragma unroll
        for (int k = 0; k < KTAPS; ++k) {
            const int idx = nl[node * KTAPS + k];
            const int src = (idx >= lo) && (idx < hi) ? idx : N_NODES;  // zero row
            const bf16x8 xf = *reinterpret_cast<const bf16x8*>(xb + (size_t)src * C_IN + lg * 8);
            const bf16x8 w0 = *reinterpret_cast<const bf16x8*>(wlay + ((size_t)(k * 2 + 0) * 64 + lane) * 8);
            const bf16x8 w1 = *reinterpret_cast<const bf16x8*>(wlay + ((size_t)(k * 2 + 1) * 64 + lane) * 8);
            acc0 = __builtin_amdgcn_mfma_f32_16x16x32_bf16(w0, xf, acc0, 0, 0, 0);
            acc1 = __builtin_amdgcn_mfma_f32_16x16x32_bf16(w1, xf, acc1, 0, 0, 0);
        }
        __syncthreads();  // keep the block's waves pass-aligned
    }

    // D layout: col = lr -> node, row = lg*4 + r -> c_out
#pragma unroll
    for (int r = 0; r < 4; ++r) {
        out[(size_t)(lg * 4 + r) * N_NODES + nb + node]      = acc0[r];
        out[(size_t)(16 + lg * 4 + r) * N_NODES + nb + node] = acc1[r];
    }

    // fused BN stats: 16-lane in-register reduce, then LDS, then global atomics
    float s0[4], q0[4], s1[4], q1[4];
#pragma unroll
    for (int r = 0; r < 4; ++r) {
        s0[r] = acc0[r]; q0[r] = acc0[r] * acc0[r];
        s1[r] = acc1[r]; q1[r] = acc1[r] * acc1[r];
    }
#pragma unroll
    for (int off = 1; off < 16; off <<= 1) {
#pragma unroll
        for (int r = 0; r < 4; ++r) {
            s0[r] += __shfl_xor(s0[r], off); q0[r] += __shfl_xor(q0[r], off);
            s1[r] += __shfl_xor(s1[r], off); q1[r] += __shfl_xor(q1[r], off);
        }
    }
    if (lr == 0) {
#pragma unroll
        for (int r = 0; r < 4; ++r) {
            atomicAdd(&bs[lg * 4 + r], s0[r]);      atomicAdd(&bq[lg * 4 + r], q0[r]);
            atomicAdd(&bs[16 + lg * 4 + r], s1[r]); atomicAdd(&bq[16 + lg * 4 + r], q1[r]);
        }
    }
    __syncthreads();
    if (threadIdx.x < C_OUT) {
        atomicAdd(&sums[threadIdx.x], bs[threadIdx.x]);
        atomicAdd(&sums[C_OUT + threadIdx.x], bq[threadIdx.x]);
    }
}

// ---- BN + ReLU in-place ----
__global__ __launch_bounds__(256) void k_bnrelu(float* __restrict__ out,
                                                const float* __restrict__ sums,
                                                const float* __restrict__ gamma,
                                                const float* __restrict__ beta) {
    const size_t gid = (size_t)blockIdx.x * 256 + threadIdx.x;  // over float4s
    const int co = (int)(gid / (N_NODES / 4));
    const float inv_n = 1.0f / (float)N_NODES;
    const float mean = sums[co] * inv_n;
    const float var  = sums[C_OUT + co] * inv_n - mean * mean;
    const float scale = rsqrtf(var + BN_EPS) * gamma[co];
    const float bias  = beta[co] - mean * scale;

    float4* p = reinterpret_cast<float4*>(out);
    float4 v = p[gid];
    v.x = fmaxf(fmaf(v.x, scale, bias), 0.0f);
    v.y = fmaxf(fmaf(v.y, scale, bias), 0.0f);
    v.z = fmaxf(fmaf(v.z, scale, bias), 0.0f);
    v.w = fmaxf(fmaf(v.w, scale, bias), 0.0f);
    p[gid] = v;
}

extern "C" void kernel_launch(void* const* d_in, const int* in_sizes, int n_in,
                              void* d_out, int out_size, void* d_ws, size_t ws_size,
                              hipStream_t stream) {
    const float* data_in = (const float*)d_in[0];
    const int*   neigh   = (const int*)d_in[1];
    const float* weight  = (const float*)d_in[2];
    const float* gamma   = (const float*)d_in[3];
    const float* beta    = (const float*)d_in[4];
    float* out = (float*)d_out;

    unsigned short* xb   = (unsigned short*)d_ws;                        // (N+1)*32 bf16
    unsigned short* wlay = xb + (size_t)(N_NODES + 1) * C_IN;            // 55296 B
    float* sums = (float*)(wlay + (size_t)KTAPS * 2 * 64 * 8);           // 64 f32

    hipMemsetAsync(sums, 0, 2 * C_OUT * sizeof(float), stream);
    k_prep<<<N_NODES / 256, 256, 0, stream>>>(data_in, weight, xb, wlay);
    k_conv_mfma<<<N_NODES / 64, 256, 0, stream>>>(xb, neigh, wlay, out, sums);
    k_bnrelu<<<(N_NODES * C_OUT / 4) / 256, 256, 0, stream>>>(out, sums, gamma, beta);
}

// Round 6
// 92.630 us; speedup vs baseline: 4.1842x; 4.1842x over previous
//
#include <hip/hip_runtime.h>

#define N_NODES 131072
#define C_IN 32
#define C_OUT 32
#define KTAPS 27
#define BN_EPS 1e-5f

typedef __bf16 bf16x8 __attribute__((ext_vector_type(8)));
typedef float  f32x4  __attribute__((ext_vector_type(4)));

// ws layout:
//   xb   : N_NODES rows x 32 bf16 (node-major features)
//   wlay : 27 taps x 2 co-halves x 64 lanes x 8 bf16  (55296 B)
//   sums : 32 sum + 32 sumsq (f32)

static __device__ __forceinline__ unsigned short f2bf(float f) {
    unsigned int u = __float_as_uint(f);
    unsigned int r = (u + 0x7FFFu + ((u >> 16) & 1u)) >> 16;  // RNE
    return (unsigned short)r;
}

// ---- prep: x transpose -> node-major bf16; block 0 also builds wlay ----
__global__ __launch_bounds__(256) void k_prep(const float* __restrict__ in,
                                              const float* __restrict__ w,
                                              unsigned short* __restrict__ xb,
                                              unsigned short* __restrict__ wlay) {
    const int n = blockIdx.x * 256 + threadIdx.x;
    unsigned short v[C_IN];
#pragma unroll
    for (int c = 0; c < C_IN; ++c) v[c] = f2bf(in[(size_t)c * N_NODES + n]);
    uint4* dst = reinterpret_cast<uint4*>(xb + (size_t)n * C_IN);
#pragma unroll
    for (int q = 0; q < 4; ++q) {
        uint4 pk;
        pk.x = (unsigned)v[q * 8 + 0] | ((unsigned)v[q * 8 + 1] << 16);
        pk.y = (unsigned)v[q * 8 + 2] | ((unsigned)v[q * 8 + 3] << 16);
        pk.z = (unsigned)v[q * 8 + 4] | ((unsigned)v[q * 8 + 5] << 16);
        pk.w = (unsigned)v[q * 8 + 6] | ((unsigned)v[q * 8 + 7] << 16);
        dst[q] = pk;
    }
    if (blockIdx.x == 0) {
        for (int g = threadIdx.x; g < KTAPS * 2 * 64; g += 256) {
            const int k = g >> 7;
            const int rem = g & 127;
            const int h = rem >> 6;
            const int l = rem & 63;
            unsigned short wv[8];
#pragma unroll
            for (int j = 0; j < 8; ++j) {
                const int c  = ((l >> 4) << 3) + j;
                const int co = (h << 4) + (l & 15);
                wv[j] = f2bf(w[(size_t)(k * C_IN + c) * C_OUT + co]);
            }
            uint4 pk;
            pk.x = (unsigned)wv[0] | ((unsigned)wv[1] << 16);
            pk.y = (unsigned)wv[2] | ((unsigned)wv[3] << 16);
            pk.z = (unsigned)wv[4] | ((unsigned)wv[5] << 16);
            pk.w = (unsigned)wv[6] | ((unsigned)wv[7] << 16);
            *reinterpret_cast<uint4*>(wlay + (size_t)g * 8) = pk;
        }
    }
}

// ---- conv: 16 nodes/wave, 9x3-tap register-pipelined phases, fused BN stats ----
__global__ __launch_bounds__(256) void k_conv_mfma(const unsigned short* __restrict__ xb,
                                                   const int* __restrict__ neigh,
                                                   const unsigned short* __restrict__ wlay,
                                                   float* __restrict__ out,
                                                   float* __restrict__ sums) {
    __shared__ float bs[C_OUT];
    __shared__ float bq[C_OUT];
    if (threadIdx.x < C_OUT) { bs[threadIdx.x] = 0.f; bq[threadIdx.x] = 0.f; }

    const int wid  = threadIdx.x >> 6;
    const int lane = threadIdx.x & 63;
    const int lr   = lane & 15;   // node offset (B/D col)
    const int lg   = lane >> 4;   // channel-slice group
    const int nb   = blockIdx.x * 64 + wid * 16;

    // all 27 neighbor indices up front (independent loads, L1-friendly lines)
    const int* nrow = neigh + (size_t)(nb + lr) * KTAPS;
    int nidx[KTAPS];
#pragma unroll
    for (int k = 0; k < KTAPS; ++k) nidx[k] = nrow[k];

    f32x4 acc0 = {0.f, 0.f, 0.f, 0.f};
    f32x4 acc1 = {0.f, 0.f, 0.f, 0.f};

    // prologue: gather batch 0
    bf16x8 xf[2][3];
#pragma unroll
    for (int j = 0; j < 3; ++j)
        xf[0][j] = *reinterpret_cast<const bf16x8*>(xb + (size_t)nidx[j] * C_IN + lg * 8);

#pragma unroll
    for (int p = 0; p < 9; ++p) {
        const int cb = p & 1;
        // 1) weight loads for this phase (issued BEFORE next gathers so the
        //    MFMA vmcnt wait leaves the next gather batch in flight)
        bf16x8 w0[3], w1[3];
#pragma unroll
        for (int j = 0; j < 3; ++j) {
            const int k = p * 3 + j;
            w0[j] = *reinterpret_cast<const bf16x8*>(wlay + ((size_t)(k * 2 + 0) * 64 + lane) * 8);
            w1[j] = *reinterpret_cast<const bf16x8*>(wlay + ((size_t)(k * 2 + 1) * 64 + lane) * 8);
        }
        // 2) issue next gather batch
        if (p < 8) {
#pragma unroll
            for (int j = 0; j < 3; ++j)
                xf[cb ^ 1][j] = *reinterpret_cast<const bf16x8*>(
                    xb + (size_t)nidx[p * 3 + 3 + j] * C_IN + lg * 8);
        }
        __builtin_amdgcn_sched_barrier(0);  // pin: loads above, MFMAs below
        // 3) MFMA on current batch
#pragma unroll
        for (int j = 0; j < 3; ++j) {
            acc0 = __builtin_amdgcn_mfma_f32_16x16x32_bf16(w0[j], xf[cb][j], acc0, 0, 0, 0);
            acc1 = __builtin_amdgcn_mfma_f32_16x16x32_bf16(w1[j], xf[cb][j], acc1, 0, 0, 0);
        }
    }

    // D layout: col = lr -> node, row = lg*4 + r -> c_out
#pragma unroll
    for (int r = 0; r < 4; ++r) {
        out[(size_t)(lg * 4 + r) * N_NODES + nb + lr]      = acc0[r];
        out[(size_t)(16 + lg * 4 + r) * N_NODES + nb + lr] = acc1[r];
    }

    // fused BN stats: 16-lane in-register reduce -> LDS -> 64 global atomics/block
    float s0[4], q0[4], s1[4], q1[4];
#pragma unroll
    for (int r = 0; r < 4; ++r) {
        s0[r] = acc0[r]; q0[r] = acc0[r] * acc0[r];
        s1[r] = acc1[r]; q1[r] = acc1[r] * acc1[r];
    }
#pragma unroll
    for (int off = 1; off < 16; off <<= 1) {
#pragma unroll
        for (int r = 0; r < 4; ++r) {
            s0[r] += __shfl_xor(s0[r], off); q0[r] += __shfl_xor(q0[r], off);
            s1[r] += __shfl_xor(s1[r], off); q1[r] += __shfl_xor(q1[r], off);
        }
    }
    __syncthreads();  // bs/bq init visible
    if (lr == 0) {
#pragma unroll
        for (int r = 0; r < 4; ++r) {
            atomicAdd(&bs[lg * 4 + r], s0[r]);      atomicAdd(&bq[lg * 4 + r], q0[r]);
            atomicAdd(&bs[16 + lg * 4 + r], s1[r]); atomicAdd(&bq[16 + lg * 4 + r], q1[r]);
        }
    }
    __syncthreads();
    if (threadIdx.x < C_OUT) {
        atomicAdd(&sums[threadIdx.x], bs[threadIdx.x]);
        atomicAdd(&sums[C_OUT + threadIdx.x], bq[threadIdx.x]);
    }
}

// ---- BN + ReLU in-place ----
__global__ __launch_bounds__(256) void k_bnrelu(float* __restrict__ out,
                                                const float* __restrict__ sums,
                                                const float* __restrict__ gamma,
                                                const float* __restrict__ beta) {
    const size_t gid = (size_t)blockIdx.x * 256 + threadIdx.x;  // over float4s
    const int co = (int)(gid / (N_NODES / 4));
    const float inv_n = 1.0f / (float)N_NODES;
    const float mean = sums[co] * inv_n;
    const float var  = sums[C_OUT + co] * inv_n - mean * mean;
    const float scale = rsqrtf(var + BN_EPS) * gamma[co];
    const float bias  = beta[co] - mean * scale;

    float4* p = reinterpret_cast<float4*>(out);
    float4 v = p[gid];
    v.x = fmaxf(fmaf(v.x, scale, bias), 0.0f);
    v.y = fmaxf(fmaf(v.y, scale, bias), 0.0f);
    v.z = fmaxf(fmaf(v.z, scale, bias), 0.0f);
    v.w = fmaxf(fmaf(v.w, scale, bias), 0.0f);
    p[gid] = v;
}

extern "C" void kernel_launch(void* const* d_in, const int* in_sizes, int n_in,
                              void* d_out, int out_size, void* d_ws, size_t ws_size,
                              hipStream_t stream) {
    const float* data_in = (const float*)d_in[0];
    const int*   neigh   = (const int*)d_in[1];
    const float* weight  = (const float*)d_in[2];
    const float* gamma   = (const float*)d_in[3];
    const float* beta    = (const float*)d_in[4];
    float* out = (float*)d_out;

    unsigned short* xb   = (unsigned short*)d_ws;                        // N*32 bf16
    unsigned short* wlay = xb + (size_t)N_NODES * C_IN;                  // 55296 B
    float* sums = (float*)(wlay + (size_t)KTAPS * 2 * 64 * 8);           // 64 f32

    hipMemsetAsync(sums, 0, 2 * C_OUT * sizeof(float), stream);
    k_prep<<<N_NODES / 256, 256, 0, stream>>>(data_in, weight, xb, wlay);
    k_conv_mfma<<<N_NODES / 64, 256, 0, stream>>>(xb, neigh, wlay, out, sums);
    k_bnrelu<<<(N_NODES * C_OUT / 4) / 256, 256, 0, stream>>>(out, sums, gamma, beta);
}

// Round 7
// 73.120 us; speedup vs baseline: 5.3006x; 1.2668x over previous
//
#include <hip/hip_runtime.h>

#define N_NODES 131072
#define C_IN 32
#define C_OUT 32
#define KTAPS 27
#define BN_EPS 1e-5f
#define NPASS 3

typedef __bf16 bf16x8 __attribute__((ext_vector_type(8)));
typedef float  f32x4  __attribute__((ext_vector_type(4)));

// ws layout:
//   xb   : (N_NODES+1) rows x 32 bf16 (row N_NODES = zeros, gather dummy target)
//   wlay : 27 taps x 2 co-halves x 64 lanes x 8 bf16  (55296 B)
//   sums : 32 sum + 32 sumsq (f32)

static __device__ __forceinline__ unsigned short f2bf(float f) {
    unsigned int u = __float_as_uint(f);
    unsigned int r = (u + 0x7FFFu + ((u >> 16) & 1u)) >> 16;  // RNE
    return (unsigned short)r;
}

// ---- prep: blocks 0..511 transpose x; block 512 builds wlay + zero row + zeroes sums ----
__global__ __launch_bounds__(256) void k_prep(const float* __restrict__ in,
                                              const float* __restrict__ w,
                                              unsigned short* __restrict__ xb,
                                              unsigned short* __restrict__ wlay,
                                              float* __restrict__ sums) {
    if (blockIdx.x < N_NODES / 256) {
        const int n = blockIdx.x * 256 + threadIdx.x;
        unsigned short v[C_IN];
#pragma unroll
        for (int c = 0; c < C_IN; ++c) v[c] = f2bf(in[(size_t)c * N_NODES + n]);
        uint4* dst = reinterpret_cast<uint4*>(xb + (size_t)n * C_IN);
#pragma unroll
        for (int q = 0; q < 4; ++q) {
            uint4 pk;
            pk.x = (unsigned)v[q * 8 + 0] | ((unsigned)v[q * 8 + 1] << 16);
            pk.y = (unsigned)v[q * 8 + 2] | ((unsigned)v[q * 8 + 3] << 16);
            pk.z = (unsigned)v[q * 8 + 4] | ((unsigned)v[q * 8 + 5] << 16);
            pk.w = (unsigned)v[q * 8 + 6] | ((unsigned)v[q * 8 + 7] << 16);
            dst[q] = pk;
        }
    } else {
        if (threadIdx.x < 4) {
            uint4 z = {0u, 0u, 0u, 0u};
            reinterpret_cast<uint4*>(xb + (size_t)N_NODES * C_IN)[threadIdx.x] = z;
        }
        if (threadIdx.x < 2 * C_OUT) sums[threadIdx.x] = 0.f;
        for (int g = threadIdx.x; g < KTAPS * 2 * 64; g += 256) {
            const int k = g >> 7;
            const int rem = g & 127;
            const int h = rem >> 6;
            const int l = rem & 63;
            unsigned short wv[8];
#pragma unroll
            for (int j = 0; j < 8; ++j) {
                const int c  = ((l >> 4) << 3) + j;
                const int co = (h << 4) + (l & 15);
                wv[j] = f2bf(w[(size_t)(k * C_IN + c) * C_OUT + co]);
            }
            uint4 pk;
            pk.x = (unsigned)wv[0] | ((unsigned)wv[1] << 16);
            pk.y = (unsigned)wv[2] | ((unsigned)wv[3] << 16);
            pk.z = (unsigned)wv[4] | ((unsigned)wv[5] << 16);
            pk.w = (unsigned)wv[6] | ((unsigned)wv[7] << 16);
            *reinterpret_cast<uint4*>(wlay + (size_t)g * 8) = pk;
        }
    }
}

// ---- conv: 512 co-resident 1024-thread blocks, 3 in-phase passes,
//      weights in LDS, 16 nodes/wave, fused BN stats ----
__global__ __launch_bounds__(1024) void k_conv_mfma(const unsigned short* __restrict__ xb,
                                                    const int* __restrict__ neigh,
                                                    const unsigned short* __restrict__ wlay,
                                                    float* __restrict__ out,
                                                    float* __restrict__ sums) {
    __shared__ unsigned short wl[KTAPS * 2 * 64 * 8];  // 55296 B
    __shared__ float bs[C_OUT];
    __shared__ float bq[C_OUT];

    {   // stage weight table (3456 uint4 over 1024 threads)
        const uint4* src = reinterpret_cast<const uint4*>(wlay);
        uint4* d = reinterpret_cast<uint4*>(wl);
        for (int i = threadIdx.x; i < KTAPS * 2 * 64; i += 1024) d[i] = src[i];
    }
    if (threadIdx.x < C_OUT) { bs[threadIdx.x] = 0.f; bq[threadIdx.x] = 0.f; }
    __syncthreads();

    const int wid  = threadIdx.x >> 6;   // 0..15
    const int lane = threadIdx.x & 63;
    const int lr   = lane & 15;          // node offset (B/D col)
    const int lg   = lane >> 4;          // channel-slice group
    const int nb   = blockIdx.x * 256 + wid * 16;

    // neighbor list for this lane's node, held in VGPRs across all passes
    const int* nrow = neigh + (size_t)(nb + lr) * KTAPS;
    int nidx[KTAPS];
#pragma unroll
    for (int k = 0; k < KTAPS; ++k) nidx[k] = nrow[k];

    f32x4 acc0 = {0.f, 0.f, 0.f, 0.f};
    f32x4 acc1 = {0.f, 0.f, 0.f, 0.f};

#pragma unroll 1
    for (int p = 0; p < NPASS; ++p) {
        const int lo = (p * N_NODES) / NPASS;
        const int hi = ((p + 1) * N_NODES) / NPASS;
#pragma unroll
        for (int k = 0; k < KTAPS; ++k) {
            const int idx = nidx[k];
            const int src = (idx >= lo) && (idx < hi) ? idx : N_NODES;  // zero row
            const bf16x8 xf = *reinterpret_cast<const bf16x8*>(xb + (size_t)src * C_IN + lg * 8);
            const bf16x8 w0 = *reinterpret_cast<const bf16x8*>(wl + ((size_t)(k * 2 + 0) * 64 + lane) * 8);
            const bf16x8 w1 = *reinterpret_cast<const bf16x8*>(wl + ((size_t)(k * 2 + 1) * 64 + lane) * 8);
            acc0 = __builtin_amdgcn_mfma_f32_16x16x32_bf16(w0, xf, acc0, 0, 0, 0);
            acc1 = __builtin_amdgcn_mfma_f32_16x16x32_bf16(w1, xf, acc1, 0, 0, 0);
        }
        __syncthreads();  // bound wave drift to one pass (keeps L2 set = one chunk)
    }

    // D layout: col = lr -> node, row = lg*4 + r -> c_out
#pragma unroll
    for (int r = 0; r < 4; ++r) {
        out[(size_t)(lg * 4 + r) * N_NODES + nb + lr]      = acc0[r];
        out[(size_t)(16 + lg * 4 + r) * N_NODES + nb + lr] = acc1[r];
    }

    // fused BN stats: 16-lane in-register reduce -> LDS atomics -> 64 global atomics/block
    float s0[4], q0[4], s1[4], q1[4];
#pragma unroll
    for (int r = 0; r < 4; ++r) {
        s0[r] = acc0[r]; q0[r] = acc0[r] * acc0[r];
        s1[r] = acc1[r]; q1[r] = acc1[r] * acc1[r];
    }
#pragma unroll
    for (int off = 1; off < 16; off <<= 1) {
#pragma unroll
        for (int r = 0; r < 4; ++r) {
            s0[r] += __shfl_xor(s0[r], off); q0[r] += __shfl_xor(q0[r], off);
            s1[r] += __shfl_xor(s1[r], off); q1[r] += __shfl_xor(q1[r], off);
        }
    }
    if (lr == 0) {
#pragma unroll
        for (int r = 0; r < 4; ++r) {
            atomicAdd(&bs[lg * 4 + r], s0[r]);      atomicAdd(&bq[lg * 4 + r], q0[r]);
            atomicAdd(&bs[16 + lg * 4 + r], s1[r]); atomicAdd(&bq[16 + lg * 4 + r], q1[r]);
        }
    }
    __syncthreads();
    if (threadIdx.x < C_OUT) {
        atomicAdd(&sums[threadIdx.x], bs[threadIdx.x]);
        atomicAdd(&sums[C_OUT + threadIdx.x], bq[threadIdx.x]);
    }
}

// ---- BN + ReLU in-place ----
__global__ __launch_bounds__(256) void k_bnrelu(float* __restrict__ out,
                                                const float* __restrict__ sums,
                                                const float* __restrict__ gamma,
                                                const float* __restrict__ beta) {
    const size_t gid = (size_t)blockIdx.x * 256 + threadIdx.x;  // over float4s
    const int co = (int)(gid / (N_NODES / 4));
    const float inv_n = 1.0f / (float)N_NODES;
    const float mean = sums[co] * inv_n;
    const float var  = sums[C_OUT + co] * inv_n - mean * mean;
    const float scale = rsqrtf(var + BN_EPS) * gamma[co];
    const float bias  = beta[co] - mean * scale;

    float4* p = reinterpret_cast<float4*>(out);
    float4 v = p[gid];
    v.x = fmaxf(fmaf(v.x, scale, bias), 0.0f);
    v.y = fmaxf(fmaf(v.y, scale, bias), 0.0f);
    v.z = fmaxf(fmaf(v.z, scale, bias), 0.0f);
    v.w = fmaxf(fmaf(v.w, scale, bias), 0.0f);
    p[gid] = v;
}

extern "C" void kernel_launch(void* const* d_in, const int* in_sizes, int n_in,
                              void* d_out, int out_size, void* d_ws, size_t ws_size,
                              hipStream_t stream) {
    const float* data_in = (const float*)d_in[0];
    const int*   neigh   = (const int*)d_in[1];
    const float* weight  = (const float*)d_in[2];
    const float* gamma   = (const float*)d_in[3];
    const float* beta    = (const float*)d_in[4];
    float* out = (float*)d_out;

    unsigned short* xb   = (unsigned short*)d_ws;                        // (N+1)*32 bf16
    unsigned short* wlay = xb + (size_t)(N_NODES + 1) * C_IN;            // 55296 B
    float* sums = (float*)(wlay + (size_t)KTAPS * 2 * 64 * 8);           // 64 f32

    k_prep<<<N_NODES / 256 + 1, 256, 0, stream>>>(data_in, weight, xb, wlay, sums);
    k_conv_mfma<<<N_NODES / 256, 1024, 0, stream>>>(xb, neigh, wlay, out, sums);
    k_bnrelu<<<(N_NODES * C_OUT / 4) / 256, 256, 0, stream>>>(out, sums, gamma, beta);
}